// Round 9
// baseline (155.272 us; speedup 1.0000x reference)
//
#include <hip/hip_runtime.h>
#include <hip/hip_bf16.h>

#define NE 32
#define MM 1024
#define KK 512
#define NN 512
#define BM 256   // rows per tile (vt = ceil(cnt/256) m-tiles per expert)
#define BN 256   // cols per tile -> 2 n-tiles
#define BK 32    // K-step; 16 iterations, ONE barrier each

typedef __attribute__((ext_vector_type(8))) short bf16x8;
typedef __attribute__((ext_vector_type(4))) float floatx4;

__device__ __forceinline__ short f2bf(float f) {
  union { __hip_bfloat16 b; short s; } u;
  u.b = __float2bfloat16(f);   // RNE
  return u.s;
}
__device__ __forceinline__ bf16x8 pack8(float4 a, float4 b) {
  return (bf16x8){ f2bf(a.x), f2bf(a.y), f2bf(a.z), f2bf(a.w),
                   f2bf(b.x), f2bf(b.y), f2bf(b.z), f2bf(b.w) };
}

// FAT-TILE (r8, verified) + ASYMMETRIC DEPTH-2 PREFETCH (this round).
// vmcnt retires in issue order, so keep the queue as
//   [A(k), B(k), A(k+1), B(k+1), A(k+2)]
// per iteration: issue B(k+1), issue A(k+2), pack A(k) (compiler waits
// vmcnt(16)), pack B(k) (vmcnt(12) -- leaves A(k+1),B(k+1),A(k+2) in
// flight). A's latency is covered by 2 iteration bodies, B's by 1 body +
// the A-pack work. Staging live = 20 float4 = 80 VGPR; with 128 acc AGPR
// this fits the 256-reg/wave budget at 2 waves/SIMD exactly.
extern "C" __global__ __launch_bounds__(512, 2)
void expert_gemm(const float* __restrict__ A, const float* __restrict__ B,
                 const int* __restrict__ cnts, float* __restrict__ C)
{
  const int b    = blockIdx.x;
  const int tid  = threadIdx.x;
  const int xcd  = b & 7;
  const int slot = b >> 3;

  int e = -1, mt = 0, nt = 0, zfill = 0;
  int base = 0;
#pragma unroll
  for (int i = 0; i < 4; ++i) {
    int ei = xcd + (i << 3);
    int vt = (cnts[ei] + 255) >> 8;    // 256-row tiles with valid rows
    int tot = vt + 4;                  // 2*vt gemm + (4-vt) zero stripes
    if (e < 0 && slot < base + tot) {
      int r = slot - base;
      int g = vt << 1;
      e = ei;
      if (r < g) { mt = r >> 1; nt = r & 1; }
      else       { zfill = 1; mt = vt + (r - g); }
    }
    base += tot;
  }
  if (e < 0) return;   // beyond this XCD's item count (uniform per block)

  if (zfill) {
    // zero-fill a 256x512 stripe (harness poisons d_out each launch)
    float* Ce = C + ((size_t)e * MM + mt * BM) * NN;
    float4 zf = make_float4(0.f, 0.f, 0.f, 0.f);
#pragma unroll
    for (int q = 0; q < 64; ++q) {
      int fidx = q * 512 + tid;
      int r = fidx >> 7, c = (fidx & 127) << 2;
      *(float4*)(Ce + (size_t)r * NN + c) = zf;
    }
    return;
  }

  // ---- GEMM tile: C[e][m0:m0+256][n0:n0+256] = A[e] @ B[e]^T ----
  const int m0 = mt * BM, n0 = nt * BN;
  const int cnt = cnts[e];
  const float* Ae = A + ((size_t)e * MM + m0) * KK;
  const float* Be = B + ((size_t)e * NN + n0) * KK;
  float* Ce = C + ((size_t)e * MM + m0) * NN + n0;

  // bf16 LDS, double-buffered. Row = 32 bf16 = 64 B = 4 x 16B units;
  // logical unit u of row r at phys unit r*4 + (u ^ (r&3)) (r8-verified).
  __shared__ __align__(16) short lA[2][BM * BK];  // 2 x 16 KB
  __shared__ __align__(16) short lB[2][BN * BK];  // 2 x 16 KB

  const int wave = tid >> 6, lane = tid & 63;
  const int wm = (wave >> 2) * 128, wn = (wave & 3) * 64;  // wave tile: 128x64
  const int fr = lane & 15, kh = lane >> 4;

  // staging map: thread t -> rows {t>>2, t>>2+128}, seg t&3 (8 floats each)
  const int row0 = tid >> 2, seg = tid & 3;
  const int wu0 = (row0 << 2) + (seg ^ (row0 & 3));           // write unit, row0
  const int wu1 = ((row0 + 128) << 2) + (seg ^ (row0 & 3));   // row0+128 (same key)

  floatx4 acc4[8][4] = {};

  // staging register sets: A has 3 live (depth-2), B has 2 live (depth-1)
  float4 aA0[4], aA1[4], aA2[4], bB0[4], bB1[4];

#define ISSUE_A(pa, KT) do {                                          \
    int colf = (KT) + (seg << 3);                                     \
    pa[0] = *(const float4*)(Ae + (size_t)row0 * KK + colf);          \
    pa[1] = *(const float4*)(Ae + (size_t)row0 * KK + colf + 4);      \
    pa[2] = *(const float4*)(Ae + (size_t)(row0+128) * KK + colf);    \
    pa[3] = *(const float4*)(Ae + (size_t)(row0+128) * KK + colf+4);  \
  } while (0)
#define ISSUE_B(pb, KT) do {                                          \
    int colf = (KT) + (seg << 3);                                     \
    pb[0] = *(const float4*)(Be + (size_t)row0 * KK + colf);          \
    pb[1] = *(const float4*)(Be + (size_t)row0 * KK + colf + 4);      \
    pb[2] = *(const float4*)(Be + (size_t)(row0+128) * KK + colf);    \
    pb[3] = *(const float4*)(Be + (size_t)(row0+128) * KK + colf+4);  \
  } while (0)

  // prologue queue: [A(0), B(0), A(1)]
  ISSUE_A(aA0, 0);
  ISSUE_B(bB0, 0);
  ISSUE_A(aA1, BK);

#pragma unroll
  for (int kt = 0; kt < KK; kt += BK) {
    const int cur = (kt >> 5) & 1;

    // issue section -- order matters for the vmcnt retire queue
    if (kt + BK < KK)     ISSUE_B(bB1, kt + BK);        // B(k+1)
    if (kt + 2 * BK < KK) ISSUE_A(aA2, kt + 2 * BK);    // A(k+2)
    __builtin_amdgcn_sched_barrier(0);   // pin issues above the packs

    // pack A(k): compiler waits vmcnt(16) -> B(k),A(k+1),B(k+1),A(k+2) in flight
    *(bf16x8*)(lA[cur] + (wu0 << 3)) = pack8(aA0[0], aA0[1]);
    *(bf16x8*)(lA[cur] + (wu1 << 3)) = pack8(aA0[2], aA0[3]);
    // pack B(k): compiler waits vmcnt(12) -> A(k+1),B(k+1),A(k+2) in flight
    *(bf16x8*)(lB[cur] + (wu0 << 3)) = pack8(bB0[0], bB0[1]);
    *(bf16x8*)(lB[cur] + (wu1 << 3)) = pack8(bB0[2], bB0[3]);

    // ONE barrier per K-step (r8-verified single-barrier argument)
    asm volatile("s_waitcnt lgkmcnt(0)" ::: "memory");
    __builtin_amdgcn_s_barrier();
    __builtin_amdgcn_sched_barrier(0);

    bf16x8 bfv[4];
#pragma unroll
    for (int j = 0; j < 4; ++j) {
      int rB = wn + (j << 4) + fr;
      bfv[j] = *(const bf16x8*)(lB[cur] + (((rB << 2) + (kh ^ (rB & 3))) << 3));
    }
    __builtin_amdgcn_s_setprio(1);
#pragma unroll
    for (int i = 0; i < 8; ++i) {
      int rA = wm + (i << 4) + fr;
      bf16x8 af = *(const bf16x8*)(lA[cur] + (((rA << 2) + (kh ^ (rA & 3))) << 3));
#pragma unroll
      for (int j = 0; j < 4; ++j)
        acc4[i][j] = __builtin_amdgcn_mfma_f32_16x16x32_bf16(af, bfv[j], acc4[i][j], 0, 0, 0);
    }
    __builtin_amdgcn_s_setprio(0);

    // rotate staging sets (renamed away by full unroll)
#pragma unroll
    for (int q = 0; q < 4; ++q) { aA0[q] = aA1[q]; aA1[q] = aA2[q]; bB0[q] = bB1[q]; }
  }
#undef ISSUE_A
#undef ISSUE_B

  // epilogue: C/D layout col=lane&15, row=(lane>>4)*4+reg (m89/m91-verified)
  const int rbase = (lane >> 4) << 2;
#pragma unroll
  for (int i = 0; i < 8; ++i) {
#pragma unroll
    for (int r = 0; r < 4; ++r) {
      int row = wm + (i << 4) + rbase + r;
      bool valid = (m0 + row) < cnt;
#pragma unroll
      for (int j = 0; j < 4; ++j) {
        int col = wn + (j << 4) + fr;
        Ce[(size_t)row * NN + col] = valid ? acc4[i][j][r] : 0.0f;
      }
    }
  }
}

extern "C" void kernel_launch(void* const* d_in, const int* in_sizes, int n_in,
                              void* d_out, int out_size, void* d_ws, size_t ws_size,
                              hipStream_t stream) {
  const float* A    = (const float*)d_in[0];
  const float* B    = (const float*)d_in[1];
  const int*   cnts = (const int*)d_in[2];
  float*       C    = (float*)d_out;

  // 8 XCDs x <=32 slots; blockIdx & 7 selects XCD (round-robin dispatch)
  hipLaunchKernelGGL(expert_gemm, dim3(256), dim3(512), 0, stream, A, B, cnts, C);
}